// Round 4
// baseline (8691.363 us; speedup 1.0000x reference)
//
#include <hip/hip_runtime.h>

// TopKActivationMLP: B=16384, IN=1024, H=2048, K=256, NC=1000
//   h0 = relu(topk256(x @ W0^T + b0))
//   h1 = relu(topk256(h0 @ W1^T + b1))
//   out = h1 @ Wc^T + bc
//
// R3: exploit top-k sparsity. Layer 0 stays dense fp64 (85% of fp64 peak).
// Top-k emits compacted (val,idx,rowptr). Layers 1-2 become SpMM over the
// 256 nonzeros/row (8x less FMA): fp64 accumulate for layer 1 (decisions
// must stay fp64-exact), fp32 for layer 2 (error ~1e-6 << 7.85e-3 threshold).

#define B_SZ 16384
#define IN_SZ 1024
#define H_SZ 2048
#define K_TOP 256
#define NC_SZ 1000
#define NCH 32  // 2048 / 64 k-chunks

// ---------- dense fp64 GEMM (layer 0): C = A @ Bt^T + bias --------------
// BM=128, BN=64, BK=16; 256 threads; 8x4 doubles per thread (stride-16).
__global__ __launch_bounds__(256, 4) void gemm_bt_v2(
    const float* __restrict__ A, const float* __restrict__ Bt,
    const float* __restrict__ bias, double* __restrict__ C,
    int M, int N, int Kd) {
  __shared__ double As[16][130];
  __shared__ double Bs[16][66];
  const int tid = threadIdx.x;
  const int tx = tid & 15;
  const int tym = tid >> 4;
  const int m0 = blockIdx.y * 128;
  const int n0 = blockIdx.x * 64;

  double acc[8][4];
#pragma unroll
  for (int i = 0; i < 8; ++i)
#pragma unroll
    for (int j = 0; j < 4; ++j) acc[i][j] = 0.0;

  for (int k0 = 0; k0 < Kd; k0 += 16) {
#pragma unroll
    for (int l = 0; l < 8; ++l) {
      const int idx = l * 256 + tid;
      const int rr = idx >> 4;
      const int kk = idx & 15;
      As[kk][rr] = (double)A[(size_t)(m0 + rr) * Kd + (k0 + kk)];
    }
#pragma unroll
    for (int l = 0; l < 4; ++l) {
      const int idx = l * 256 + tid;
      const int rr = idx >> 4;
      const int kk = idx & 15;
      Bs[kk][rr] = (double)Bt[(size_t)(n0 + rr) * Kd + (k0 + kk)];
    }
    __syncthreads();
#pragma unroll 4
    for (int kk = 0; kk < 16; ++kk) {
      double a[8], b[4];
#pragma unroll
      for (int i = 0; i < 8; ++i) a[i] = As[kk][tym + 16 * i];
#pragma unroll
      for (int j = 0; j < 4; ++j) b[j] = Bs[kk][tx + 16 * j];
#pragma unroll
      for (int i = 0; i < 8; ++i)
#pragma unroll
        for (int j = 0; j < 4; ++j) acc[i][j] = fma(a[i], b[j], acc[i][j]);
    }
    __syncthreads();
  }
#pragma unroll
  for (int i = 0; i < 8; ++i) {
    const int r = m0 + tym + 16 * i;
#pragma unroll
    for (int j = 0; j < 4; ++j) {
      const int c = n0 + tx + 16 * j;
      C[(size_t)r * N + c] = acc[i][j] + (double)bias[c];
    }
  }
}

__device__ __forceinline__ int blockReduceSum(int v, int* sred) {
#pragma unroll
  for (int o = 32; o > 0; o >>= 1) v += __shfl_down(v, o);
  const int tid = threadIdx.x;
  if ((tid & 63) == 0) sred[tid >> 6] = v;
  __syncthreads();
  int t = 0;
  if (tid < 4) t = sred[tid];
  t += __shfl_down(t, 2);
  t += __shfl_down(t, 1);
  if (tid == 0) sred[0] = t;
  __syncthreads();
  const int r = sred[0];
  __syncthreads();
  return r;
}

// ---------- top-k select + compact -------------------------------------
// Input: dense fp64 row of 2048. Output: vals[256] (relu'd, ascending index),
// idxs[256], rowptr[33] (per-64-chunk offsets). One 256-thread block per row.
__global__ __launch_bounds__(256) void topk_compact(
    const double* __restrict__ h, double* __restrict__ vals,
    int* __restrict__ idxs, int* __restrict__ rowptr) {
  __shared__ int sred[4];
  __shared__ int scnt;
  __shared__ unsigned long long ckey[128];
  __shared__ int cidx[128];
  __shared__ double sval[H_SZ];          // masked values
  __shared__ unsigned char sflag[H_SZ];  // keep flags
  __shared__ int swsum[4];
  __shared__ int schunk[NCH];
  const int tid = threadIdx.x;
  const double* hr = h + (size_t)blockIdx.x * H_SZ;

  double myv[8];
  unsigned long long myk64[8];
  unsigned int myk[8];
#pragma unroll
  for (int l = 0; l < 8; ++l) {
    const int i = l * 256 + tid;
    const double v = hr[i];
    myv[l] = v;
    unsigned long long b = (unsigned long long)__double_as_longlong(v);
    unsigned long long u =
        (b & 0x8000000000000000ULL) ? ~b : (b | 0x8000000000000000ULL);
    myk64[l] = u;
    myk[l] = (unsigned int)(u >> 32);
  }

  // radix select K-th largest on high-32 key
  unsigned int prefix = 0;
  int remaining = K_TOP;
  for (int b = 31; b >= 0; --b) {
    const unsigned int bit = 1u << b;
    const unsigned int hi_mask = ~((bit << 1) - 1u);
    int cnt = 0;
#pragma unroll
    for (int l = 0; l < 8; ++l) {
      const unsigned int u = myk[l];
      cnt += (((u & hi_mask) == prefix) && (u & bit)) ? 1 : 0;
    }
    const int total = blockReduceSum(cnt, sred);
    if (total >= remaining) prefix |= bit;
    else remaining -= total;
  }
  const unsigned int T = prefix;

  int cg = 0, ce = 0;
#pragma unroll
  for (int l = 0; l < 8; ++l) {
    cg += (myk[l] > T) ? 1 : 0;
    ce += (myk[l] == T) ? 1 : 0;
  }
  const int count_gt = blockReduceSum(cg, sred);
  const int count_eq = blockReduceSum(ce, sred);
  const int need_eq = K_TOP - count_gt;

  bool keep[8];
#pragma unroll
  for (int l = 0; l < 8; ++l) keep[l] = (myk[l] > T);

  if (count_eq == need_eq) {
#pragma unroll
    for (int l = 0; l < 8; ++l) keep[l] = keep[l] || (myk[l] == T);
  } else {
    if (tid == 0) scnt = 0;
    __syncthreads();
    int mypos[8];
#pragma unroll
    for (int l = 0; l < 8; ++l) mypos[l] = -1;
#pragma unroll
    for (int l = 0; l < 8; ++l) {
      if (myk[l] == T) {
        const int p = atomicAdd(&scnt, 1);
        if (p < 128) {
          ckey[p] = myk64[l];
          cidx[p] = l * 256 + tid;
          mypos[l] = p;
        }
      }
    }
    __syncthreads();
    const int c = (scnt < 128) ? scnt : 128;
#pragma unroll
    for (int l = 0; l < 8; ++l) {
      if (mypos[l] >= 0) {
        const unsigned long long k = ckey[mypos[l]];
        const int ii = cidx[mypos[l]];
        int rank = 0;
        for (int j = 0; j < c; ++j)
          rank += ((ckey[j] > k) || (ckey[j] == k && cidx[j] < ii)) ? 1 : 0;
        keep[l] = (rank < need_eq);
      }
    }
  }

  // publish flags + relu'd values
#pragma unroll
  for (int l = 0; l < 8; ++l) {
    const int i = l * 256 + tid;
    sflag[i] = keep[l] ? 1 : 0;
    sval[i] = (keep[l] && myv[l] > 0.0) ? myv[l] : 0.0;
  }
  __syncthreads();

  // compact: thread t owns contiguous elements [8t, 8t+8) (one k-chunk each,
  // chunk id = t>>3). Exclusive scan over threads -> ascending-index order.
  const int base_i = tid * 8;
  int cnt = 0;
  int pre[8];
#pragma unroll
  for (int j = 0; j < 8; ++j) {
    pre[j] = cnt;
    cnt += sflag[base_i + j];
  }
  int inc = cnt;
#pragma unroll
  for (int o = 1; o < 64; o <<= 1) {
    const int t = __shfl_up(inc, o);
    if ((tid & 63) >= o) inc += t;
  }
  if ((tid & 63) == 63) swsum[tid >> 6] = inc;
  int gsum = cnt;
#pragma unroll
  for (int o = 1; o < 8; o <<= 1) gsum += __shfl_xor(gsum, o);
  if ((tid & 7) == 0) schunk[tid >> 3] = gsum;
  __syncthreads();

  int wbase = 0;
  for (int w = 0; w < (tid >> 6); ++w) wbase += swsum[w];
  const int ebase = wbase + inc - cnt;

  double* vr = vals + (size_t)blockIdx.x * K_TOP;
  int* ir = idxs + (size_t)blockIdx.x * K_TOP;
#pragma unroll
  for (int j = 0; j < 8; ++j) {
    if (sflag[base_i + j]) {
      const int pos = ebase + pre[j];
      if (pos < K_TOP) {
        vr[pos] = sval[base_i + j];
        ir[pos] = base_i + j;
      }
    }
  }
  if (tid == 0) {
    int* rp = rowptr + (size_t)blockIdx.x * (NCH + 1);
    int s = 0;
    for (int c = 0; c < NCH; ++c) {
      rp[c] = s;
      s += schunk[c];
    }
    rp[NCH] = (s < K_TOP) ? s : K_TOP;
  }
}

// ---------- 32x32-tiled transpose: out[k][n] = in[n][k] ------------------
__global__ __launch_bounds__(256) void transpose32(
    const float* __restrict__ in, float* __restrict__ out, int N, int Kd) {
  __shared__ float t[32][33];
  const int bx = blockIdx.x * 32;  // k
  const int by = blockIdx.y * 32;  // n
#pragma unroll
  for (int s = 0; s < 32; s += 8) {
    const int n = by + threadIdx.y + s;
    const int k = bx + threadIdx.x;
    t[threadIdx.y + s][threadIdx.x] =
        (n < N && k < Kd) ? in[(size_t)n * Kd + k] : 0.f;
  }
  __syncthreads();
#pragma unroll
  for (int s = 0; s < 32; s += 8) {
    const int k = bx + threadIdx.y + s;
    const int n = by + threadIdx.x;
    if (k < Kd && n < N) out[(size_t)k * N + n] = t[threadIdx.x][threadIdx.y + s];
  }
}

// ---------- SpMM: out[r][n] = bias[n] + sum_p vals[r][p]*WT[idx[r][p]][n] --
// WT: [Kd][N] row-major fp32. 128 rows x 64 cols per block, 64-k chunks
// staged in LDS (stride 68 floats: 16B-aligned b128 reads, rotating banks).
template <typename ACC_T, typename OUT_T>
__global__ __launch_bounds__(256) void spmm_topk(
    const double* __restrict__ vals, const int* __restrict__ idxs,
    const int* __restrict__ rowptr, const float* __restrict__ WT,
    const float* __restrict__ bias, OUT_T* __restrict__ out,
    int R, int N, int Kd) {
  __shared__ float Ws[64][68];
  const int tid = threadIdx.x;
  const int tx = tid & 15;   // owns cols n0 + tx*4 .. +3
  const int ty = tid >> 4;   // owns rows r0 + ty + 16*i
  const int r0 = blockIdx.y * 128;
  const int n0 = blockIdx.x * 64;
  const int nch = Kd >> 6;

  ACC_T acc[8][4];
#pragma unroll
  for (int i = 0; i < 8; ++i)
#pragma unroll
    for (int j = 0; j < 4; ++j) acc[i][j] = (ACC_T)0;

  for (int c = 0; c < nch; ++c) {
    const int k0 = c << 6;
#pragma unroll
    for (int l = 0; l < 16; ++l) {
      const int idx = l * 256 + tid;
      const int kk = idx >> 6;
      const int nn = idx & 63;
      const int n = n0 + nn;
      Ws[kk][nn] = (n < N) ? WT[(size_t)(k0 + kk) * N + n] : 0.f;
    }
    __syncthreads();
#pragma unroll
    for (int i = 0; i < 8; ++i) {
      const int r = r0 + ty + 16 * i;
      const int* rp = rowptr + (size_t)r * (NCH + 1);
      const int lo = rp[c];
      const int hi = rp[c + 1];
      const double* vr = vals + (size_t)r * K_TOP;
      const int* ir = idxs + (size_t)r * K_TOP;
      for (int p = lo; p < hi; ++p) {
        const ACC_T v = (ACC_T)vr[p];
        const int k = ir[p] - k0;
        const float4 w = *(const float4*)&Ws[k][tx * 4];
        acc[i][0] += v * (ACC_T)w.x;
        acc[i][1] += v * (ACC_T)w.y;
        acc[i][2] += v * (ACC_T)w.z;
        acc[i][3] += v * (ACC_T)w.w;
      }
    }
    __syncthreads();
  }

#pragma unroll
  for (int i = 0; i < 8; ++i) {
    const int r = r0 + ty + 16 * i;
#pragma unroll
    for (int j = 0; j < 4; ++j) {
      const int n = n0 + tx * 4 + j;
      if (n < N) out[(size_t)r * N + n] = (OUT_T)(acc[i][j] + (ACC_T)bias[n]);
    }
  }
}

extern "C" void kernel_launch(void* const* d_in, const int* in_sizes, int n_in,
                              void* d_out, int out_size, void* d_ws, size_t ws_size,
                              hipStream_t stream) {
  const float* x  = (const float*)d_in[0];
  const float* W0 = (const float*)d_in[1];
  const float* b0 = (const float*)d_in[2];
  const float* W1 = (const float*)d_in[3];
  const float* b1 = (const float*)d_in[4];
  const float* Wc = (const float*)d_in[5];
  const float* bc = (const float*)d_in[6];
  float* out = (float*)d_out;

  // ---- workspace carve ----
  auto align256 = [](size_t v) { return (v + 255) & ~(size_t)255; };
  char* base = (char*)d_ws;
  size_t off = 0;
  float* W1T = (float*)(base + off);
  off = align256(off + (size_t)H_SZ * H_SZ * sizeof(float));      // 16.8 MB
  float* WcT = (float*)(base + off);
  off = align256(off + (size_t)H_SZ * NC_SZ * sizeof(float));     // 8.2 MB
  const size_t fixed = off;

  // per-row: dense 2048*8 + vals 256*8 + idx 256*4 + rowptr 33*4
  const size_t per_row = (size_t)H_SZ * 8 + K_TOP * 8 + K_TOP * 4 + (NCH + 1) * 4;
  int chunkB = B_SZ;
  while (fixed + (size_t)chunkB * per_row + 4096 > ws_size && chunkB > 1024)
    chunkB >>= 1;

  double* hd = (double*)(base + off);
  off = align256(off + (size_t)chunkB * H_SZ * sizeof(double));
  double* vals = (double*)(base + off);
  off = align256(off + (size_t)chunkB * K_TOP * sizeof(double));
  int* idxs = (int*)(base + off);
  off = align256(off + (size_t)chunkB * K_TOP * sizeof(int));
  int* rowptr = (int*)(base + off);

  const dim3 blk(256);
  // one-time weight transposes (must run every call; ~25 MB, trivial)
  transpose32<<<dim3(H_SZ / 32, H_SZ / 32), dim3(32, 8), 0, stream>>>(
      W1, W1T, H_SZ, H_SZ);
  transpose32<<<dim3(H_SZ / 32, (NC_SZ + 31) / 32), dim3(32, 8), 0, stream>>>(
      Wc, WcT, NC_SZ, H_SZ);

  for (int m0 = 0; m0 < B_SZ; m0 += chunkB) {
    const int M = chunkB;
    // layer 0: dense fp64
    gemm_bt_v2<<<dim3(H_SZ / 64, M / 128), blk, 0, stream>>>(
        x + (size_t)m0 * IN_SZ, W0, b0, hd, M, H_SZ, IN_SZ);
    topk_compact<<<dim3(M), blk, 0, stream>>>(hd, vals, idxs, rowptr);
    // layer 1: fp64 SpMM (reuses hd as output; input is vals/idxs)
    spmm_topk<double, double><<<dim3(H_SZ / 64, M / 128), blk, 0, stream>>>(
        vals, idxs, rowptr, W1T, b1, hd, M, H_SZ, H_SZ);
    topk_compact<<<dim3(M), blk, 0, stream>>>(hd, vals, idxs, rowptr);
    // layer 2: fp32 SpMM straight to output
    spmm_topk<float, float><<<dim3((NC_SZ + 63) / 64, M / 128), blk, 0, stream>>>(
        vals, idxs, rowptr, WcT, bc, out + (size_t)m0 * NC_SZ, M, NC_SZ, H_SZ);
  }
}

// Round 5
// 5204.799 us; speedup vs baseline: 1.6699x; 1.6699x over previous
//
#include <hip/hip_runtime.h>

// TopKActivationMLP: B=16384, IN=1024, H=2048, K=256, NC=1000
//   h0 = relu(topk256(x @ W0^T + b0))
//   h1 = relu(topk256(h0 @ W1^T + b1))
//   out = h1 @ Wc^T + bc
//
// R4: layer 0 dense fp64 (85% of fp64 peak). Top-k emits exactly-256
// (val f64, idx) per row. Layers 1-2: fixed-trip SpMM — W col-slab (8 cols,
// FULL k range) staged in 64KB LDS, flat p=0..255 loop (unrollable, latency
// tolerant; R3's variable-trip rowptr loop was the latency killer).
// Layer-1 accumulates f64 (top-k decisions must stay exact), layer-2 f32.

#define B_SZ 16384
#define IN_SZ 1024
#define H_SZ 2048
#define K_TOP 256
#define NC_SZ 1000
#define NC_PAD 1008  // 126 blocks of 8

// ---------- dense fp64 GEMM (layer 0): C = A @ Bt^T + bias --------------
__global__ __launch_bounds__(256, 4) void gemm_bt_v2(
    const float* __restrict__ A, const float* __restrict__ Bt,
    const float* __restrict__ bias, double* __restrict__ C,
    int M, int N, int Kd) {
  __shared__ double As[16][130];
  __shared__ double Bs[16][66];
  const int tid = threadIdx.x;
  const int tx = tid & 15;
  const int tym = tid >> 4;
  const int m0 = blockIdx.y * 128;
  const int n0 = blockIdx.x * 64;

  double acc[8][4];
#pragma unroll
  for (int i = 0; i < 8; ++i)
#pragma unroll
    for (int j = 0; j < 4; ++j) acc[i][j] = 0.0;

  for (int k0 = 0; k0 < Kd; k0 += 16) {
#pragma unroll
    for (int l = 0; l < 8; ++l) {
      const int idx = l * 256 + tid;
      const int rr = idx >> 4;
      const int kk = idx & 15;
      As[kk][rr] = (double)A[(size_t)(m0 + rr) * Kd + (k0 + kk)];
    }
#pragma unroll
    for (int l = 0; l < 4; ++l) {
      const int idx = l * 256 + tid;
      const int rr = idx >> 4;
      const int kk = idx & 15;
      Bs[kk][rr] = (double)Bt[(size_t)(n0 + rr) * Kd + (k0 + kk)];
    }
    __syncthreads();
#pragma unroll 4
    for (int kk = 0; kk < 16; ++kk) {
      double a[8], b[4];
#pragma unroll
      for (int i = 0; i < 8; ++i) a[i] = As[kk][tym + 16 * i];
#pragma unroll
      for (int j = 0; j < 4; ++j) b[j] = Bs[kk][tx + 16 * j];
#pragma unroll
      for (int i = 0; i < 8; ++i)
#pragma unroll
        for (int j = 0; j < 4; ++j) acc[i][j] = fma(a[i], b[j], acc[i][j]);
    }
    __syncthreads();
  }
#pragma unroll
  for (int i = 0; i < 8; ++i) {
    const int r = m0 + tym + 16 * i;
#pragma unroll
    for (int j = 0; j < 4; ++j) {
      const int c = n0 + tx + 16 * j;
      C[(size_t)r * N + c] = acc[i][j] + (double)bias[c];
    }
  }
}

__device__ __forceinline__ int blockReduceSum(int v, int* sred) {
#pragma unroll
  for (int o = 32; o > 0; o >>= 1) v += __shfl_down(v, o);
  const int tid = threadIdx.x;
  if ((tid & 63) == 0) sred[tid >> 6] = v;
  __syncthreads();
  int t = 0;
  if (tid < 4) t = sred[tid];
  t += __shfl_down(t, 2);
  t += __shfl_down(t, 1);
  if (tid == 0) sred[0] = t;
  __syncthreads();
  const int r = sred[0];
  __syncthreads();
  return r;
}

// ---------- top-k select + compact to exactly 256 (pv f64, pi idx) -------
__global__ __launch_bounds__(256) void topk_compact(
    const double* __restrict__ h, double* __restrict__ pv,
    int* __restrict__ pi) {
  __shared__ int sred[4];
  __shared__ int scnt;
  __shared__ unsigned long long ckey[128];
  __shared__ int cidx[128];
  __shared__ double sval[H_SZ];
  __shared__ unsigned char sflag[H_SZ];
  __shared__ int swsum[4];
  const int tid = threadIdx.x;
  const double* hr = h + (size_t)blockIdx.x * H_SZ;

  double myv[8];
  unsigned long long myk64[8];
  unsigned int myk[8];
#pragma unroll
  for (int l = 0; l < 8; ++l) {
    const int i = l * 256 + tid;
    const double v = hr[i];
    myv[l] = v;
    unsigned long long b = (unsigned long long)__double_as_longlong(v);
    unsigned long long u =
        (b & 0x8000000000000000ULL) ? ~b : (b | 0x8000000000000000ULL);
    myk64[l] = u;
    myk[l] = (unsigned int)(u >> 32);
  }

  unsigned int prefix = 0;
  int remaining = K_TOP;
  for (int b = 31; b >= 0; --b) {
    const unsigned int bit = 1u << b;
    const unsigned int hi_mask = ~((bit << 1) - 1u);
    int cnt = 0;
#pragma unroll
    for (int l = 0; l < 8; ++l) {
      const unsigned int u = myk[l];
      cnt += (((u & hi_mask) == prefix) && (u & bit)) ? 1 : 0;
    }
    const int total = blockReduceSum(cnt, sred);
    if (total >= remaining) prefix |= bit;
    else remaining -= total;
  }
  const unsigned int T = prefix;

  int cg = 0, ce = 0;
#pragma unroll
  for (int l = 0; l < 8; ++l) {
    cg += (myk[l] > T) ? 1 : 0;
    ce += (myk[l] == T) ? 1 : 0;
  }
  const int count_gt = blockReduceSum(cg, sred);
  const int count_eq = blockReduceSum(ce, sred);
  const int need_eq = K_TOP - count_gt;

  bool keep[8];
#pragma unroll
  for (int l = 0; l < 8; ++l) keep[l] = (myk[l] > T);

  if (count_eq == need_eq) {
#pragma unroll
    for (int l = 0; l < 8; ++l) keep[l] = keep[l] || (myk[l] == T);
  } else {
    // rare: high-32 boundary collision -> exact 64-bit + index resolve
    if (tid == 0) scnt = 0;
    __syncthreads();
    int mypos[8];
#pragma unroll
    for (int l = 0; l < 8; ++l) mypos[l] = -1;
#pragma unroll
    for (int l = 0; l < 8; ++l) {
      if (myk[l] == T) {
        const int p = atomicAdd(&scnt, 1);
        if (p < 128) {
          ckey[p] = myk64[l];
          cidx[p] = l * 256 + tid;
          mypos[l] = p;
        }
      }
    }
    __syncthreads();
    const int c = (scnt < 128) ? scnt : 128;
#pragma unroll
    for (int l = 0; l < 8; ++l) {
      if (mypos[l] >= 0) {
        const unsigned long long k = ckey[mypos[l]];
        const int ii = cidx[mypos[l]];
        int rank = 0;
        for (int j = 0; j < c; ++j)
          rank += ((ckey[j] > k) || (ckey[j] == k && cidx[j] < ii)) ? 1 : 0;
        keep[l] = (rank < need_eq);
      }
    }
  }

#pragma unroll
  for (int l = 0; l < 8; ++l) {
    const int i = l * 256 + tid;
    sflag[i] = keep[l] ? 1 : 0;
    sval[i] = (keep[l] && myv[l] > 0.0) ? myv[l] : 0.0;
  }
  __syncthreads();

  // compact: thread t owns [8t, 8t+8); exclusive scan -> ascending index
  const int base_i = tid * 8;
  int cnt = 0;
  int pre[8];
#pragma unroll
  for (int j = 0; j < 8; ++j) {
    pre[j] = cnt;
    cnt += sflag[base_i + j];
  }
  int inc = cnt;
#pragma unroll
  for (int o = 1; o < 64; o <<= 1) {
    const int t = __shfl_up(inc, o);
    if ((tid & 63) >= o) inc += t;
  }
  if ((tid & 63) == 63) swsum[tid >> 6] = inc;
  __syncthreads();

  int wbase = 0;
  for (int w = 0; w < (tid >> 6); ++w) wbase += swsum[w];
  const int ebase = wbase + inc - cnt;

  double* pvr = pv + (size_t)blockIdx.x * K_TOP;
  int* pir = pi + (size_t)blockIdx.x * K_TOP;
#pragma unroll
  for (int j = 0; j < 8; ++j) {
    if (sflag[base_i + j]) {
      const int pos = ebase + pre[j];
      if (pos < K_TOP) {
        pvr[pos] = sval[base_i + j];
        pir[pos] = base_i + j;
      }
    }
  }
}

// ---------- pack W [N][K] -> blocked [cb][k][8], cb = n>>3 ---------------
__global__ __launch_bounds__(256) void pack_w_blocked(
    const float* __restrict__ in, float* __restrict__ out, int N, int Kd,
    int Npad) {
  __shared__ float t[32][33];
  const int bx = blockIdx.x * 32;  // k
  const int by = blockIdx.y * 32;  // n
#pragma unroll
  for (int s = 0; s < 32; s += 8) {
    const int n = by + threadIdx.y + s;
    const int k = bx + threadIdx.x;
    t[threadIdx.y + s][threadIdx.x] =
        (n < N && k < Kd) ? in[(size_t)n * Kd + k] : 0.f;
  }
  __syncthreads();
#pragma unroll
  for (int s = 0; s < 32; s += 8) {
    const int k = bx + threadIdx.y + s;
    const int n = by + threadIdx.x;
    if (k < Kd && n < Npad)
      out[(size_t)(n >> 3) * (Kd * 8) + (size_t)k * 8 + (n & 7)] =
          t[threadIdx.x][threadIdx.y + s];
  }
}

// ---------- fixed-trip SpMM over 8-col W slab ----------------------------
// Wblk[cb]: [2048][8] fp32 staged in 64KB LDS (full k range -> flat p loop).
// Thread: cols 2c,2c+1 of slab; 64 rows/pass, rowsPerBlock/64 passes.
template <typename ACC_T, typename OUT_T>
__global__ __launch_bounds__(256) void spmm8(
    const double* __restrict__ pv, const int* __restrict__ pi,
    const float* __restrict__ Wblk, const float* __restrict__ bias,
    OUT_T* __restrict__ out, int rowsPerBlock, int Ncols, int strideN) {
  __shared__ float Ws[H_SZ * 8];  // 64 KB
  const int tid = threadIdx.x;
  const int cb = blockIdx.x;
  const float* src = Wblk + (size_t)cb * (H_SZ * 8);
#pragma unroll
  for (int i = 0; i < 16; ++i)
    ((float4*)Ws)[i * 256 + tid] = ((const float4*)src)[i * 256 + tid];
  __syncthreads();

  const int c2 = (tid & 3) * 2;  // 0,2,4,6
  const int lr = tid >> 2;       // 0..63
  const int r0 = blockIdx.y * rowsPerBlock;
  const int n = cb * 8 + c2;

  for (int pass = 0; pass < rowsPerBlock / 64; ++pass) {
    const int r = r0 + pass * 64 + lr;
    const double* pvr = pv + (size_t)r * K_TOP;
    const int* pir = pi + (size_t)r * K_TOP;
    ACC_T a0 = (ACC_T)0, a1 = (ACC_T)0;
#pragma unroll 8
    for (int p = 0; p < K_TOP; ++p) {
      const ACC_T v = (ACC_T)pvr[p];
      const int k = pir[p];
      const float2 w = *(const float2*)&Ws[k * 8 + c2];
      a0 += (ACC_T)w.x * v;
      a1 += (ACC_T)w.y * v;
    }
    if (n < Ncols)
      out[(size_t)r * strideN + n] = (OUT_T)(a0 + (ACC_T)bias[n]);
    if (n + 1 < Ncols)
      out[(size_t)r * strideN + n + 1] = (OUT_T)(a1 + (ACC_T)bias[n + 1]);
  }
}

extern "C" void kernel_launch(void* const* d_in, const int* in_sizes, int n_in,
                              void* d_out, int out_size, void* d_ws, size_t ws_size,
                              hipStream_t stream) {
  const float* x  = (const float*)d_in[0];
  const float* W0 = (const float*)d_in[1];
  const float* b0 = (const float*)d_in[2];
  const float* W1 = (const float*)d_in[3];
  const float* b1 = (const float*)d_in[4];
  const float* Wc = (const float*)d_in[5];
  const float* bc = (const float*)d_in[6];
  float* out = (float*)d_out;

  auto align256 = [](size_t v) { return (v + 255) & ~(size_t)255; };
  char* base = (char*)d_ws;
  size_t off = 0;
  float* W1blk = (float*)(base + off);
  off = align256(off + (size_t)H_SZ * H_SZ * sizeof(float));       // 16.8 MB
  float* Wcblk = (float*)(base + off);
  off = align256(off + (size_t)H_SZ * NC_PAD * sizeof(float));     // 8.26 MB
  const size_t fixed = off;

  const size_t per_row =
      (size_t)H_SZ * 8 + K_TOP * 8 + K_TOP * 4;  // hd + pv + pi
  int chunkB = B_SZ;
  while (fixed + (size_t)chunkB * per_row + 4096 > ws_size && chunkB > 512)
    chunkB >>= 1;

  double* hd = (double*)(base + off);
  off = align256(off + (size_t)chunkB * H_SZ * sizeof(double));
  double* pv = (double*)(base + off);
  off = align256(off + (size_t)chunkB * K_TOP * sizeof(double));
  int* pi = (int*)(base + off);

  const dim3 blk(256);
  // one-time weight pack to blocked layout (coalesced LDS staging later)
  pack_w_blocked<<<dim3(H_SZ / 32, H_SZ / 32), dim3(32, 8), 0, stream>>>(
      W1, W1blk, H_SZ, H_SZ, H_SZ);
  pack_w_blocked<<<dim3(H_SZ / 32, (NC_PAD + 31) / 32), dim3(32, 8), 0,
                   stream>>>(Wc, Wcblk, NC_SZ, H_SZ, NC_PAD);

  const int RPB = 512;  // rows per spmm block (chunkB always divisible)
  for (int m0 = 0; m0 < B_SZ; m0 += chunkB) {
    const int M = chunkB;
    // layer 0: dense fp64
    gemm_bt_v2<<<dim3(H_SZ / 64, M / 128), blk, 0, stream>>>(
        x + (size_t)m0 * IN_SZ, W0, b0, hd, M, H_SZ, IN_SZ);
    topk_compact<<<dim3(M), blk, 0, stream>>>(hd, pv, pi);
    // layer 1: f64-exact SpMM -> dense hd
    spmm8<double, double><<<dim3(H_SZ / 8, M / RPB), blk, 0, stream>>>(
        pv, pi, W1blk, b1, hd, RPB, H_SZ, H_SZ);
    topk_compact<<<dim3(M), blk, 0, stream>>>(hd, pv, pi);
    // layer 2: f32 SpMM -> output
    spmm8<float, float><<<dim3(NC_PAD / 8, M / RPB), blk, 0, stream>>>(
        pv, pi, Wcblk, bc, out + (size_t)m0 * NC_SZ, RPB, NC_SZ, NC_SZ);
  }
}